// Round 12
// baseline (241.567 us; speedup 1.0000x reference)
//
#include <hip/hip_runtime.h>
#include <cstddef>
#include <cstdint>

// ---------------------------------------------------------------------------
// MultiHeadSelfAttention: x(4,2048,1024) fp32, W(3072,1024) fp32, Wo(1024,1024)
// Pipeline (5 launches): cvt_all | GEMM1 qkv | prep (K-rope + V-transpose) |
// flash attn (Q-rope in-register) | GEMM2
// r22: GEMM double-buffered DMA (attn-proven pattern). r21's loop drained
// vmcnt(0) immediately after issuing the tile's DMAs -> full HBM latency
// exposed every K-step (MfmaUtil 32%). Now: issue DMA(t+1) into buf^1,
// compute tile t, ONE barrier at iter end (readers-done + DMA drained with
// the whole MFMA phase to cover it). LDS 64KB -> still 2 blocks/CU
// (measured cap). BK=64 + XOR-granule swizzle kept (r21: conflicts 0).
// cvt_all/prep/attn identical to r21 (240.7us baseline).
// ---------------------------------------------------------------------------

typedef unsigned short u16;
typedef short bf16x8 __attribute__((ext_vector_type(8)));   // 8 bf16 = 4 VGPRs
typedef float f32x4 __attribute__((ext_vector_type(4)));

#define B_   4
#define L_   2048
#define H_   16
#define DH_  64
#define D_   1024
#define E3_  3072

__device__ __forceinline__ u16 f2bf(float f) {            // RNE f32 -> bf16
  unsigned int u = __float_as_uint(f);
  u += 0x7fffu + ((u >> 16) & 1u);
  return (u16)(u >> 16);
}
__device__ __forceinline__ float bf2f(u16 h) {
  return __uint_as_float(((unsigned int)h) << 16);
}
// round-half-up pack of two f32 -> bf16x2 (5 VALU ops)
__device__ __forceinline__ unsigned pk2(float a, float b) {
  return ((__float_as_uint(a) + 0x8000u) >> 16) |
         ((__float_as_uint(b) + 0x8000u) & 0xffff0000u);
}
__device__ __forceinline__ float fexp2(float x) {
#if __has_builtin(__builtin_amdgcn_exp2f)
  return __builtin_amdgcn_exp2f(x);
#else
  return exp2f(x);
#endif
}

// async global->LDS DMA, 16 bytes/lane. LDS dest = wave-uniform base + lane*16
__device__ __forceinline__ void gload_lds16(const void* g, void* l) {
  auto gp = reinterpret_cast<const uint32_t __attribute__((address_space(1)))*>(
      reinterpret_cast<uintptr_t>(g));
  auto lp = reinterpret_cast<uint32_t __attribute__((address_space(3)))*>(
      reinterpret_cast<uintptr_t>(l));
  __builtin_amdgcn_global_load_lds(gp, lp, 16, 0, 0);
}

// ---------------------------------------------------------------- cvt fp32->bf16 (x | W | Wo)
// flat 16B-unit index over all three buffers: 1048576 + 393216 + 131072 =
// 1572864 = 6144 blocks x 256 (exact, no bounds check).
__global__ __launch_bounds__(256) void cvt_all(const float* __restrict__ x,
                                               const float* __restrict__ W,
                                               const float* __restrict__ Wo,
                                               u16* __restrict__ xb,
                                               u16* __restrict__ Wb,
                                               u16* __restrict__ Wob) {
  int i = blockIdx.x * 256 + threadIdx.x;
  const float* in;
  u16* out;
  int off;
  if (i < 1048576) {
    in = x; out = xb; off = i;
  } else if (i < 1441792) {
    in = W; out = Wb; off = i - 1048576;
  } else {
    in = Wo; out = Wob; off = i - 1441792;
  }
  const float4* p = (const float4*)in;
  float4 a = p[2 * off], b = p[2 * off + 1];
  uint4 o;
  o.x = (unsigned)f2bf(a.x) | ((unsigned)f2bf(a.y) << 16);
  o.y = (unsigned)f2bf(a.z) | ((unsigned)f2bf(a.w) << 16);
  o.z = (unsigned)f2bf(b.x) | ((unsigned)f2bf(b.y) << 16);
  o.w = (unsigned)f2bf(b.z) | ((unsigned)f2bf(b.w) << 16);
  ((uint4*)out)[off] = o;
}

// ---------------------------------------------------------------- GEMM C = A * B^T
// 128x128 block tile, 4 waves (2x2 of 64x64), BK=64, double-buffered DMA:
// issue DMA(t+1) -> MFMA tile t -> one barrier (readers done + DMA drained
// under the compute phase). global_load_lds width=16, linear dest, XOR
// granule swizzle (source pre-swizzled (l&7)^(l>>3), read granule
// (ks*4+quad)^(l15&7); conflict-free, measured 0 in r21). Scalar-store
// epilogue (vectorized variants measured slower: r15/r19).
template <bool OUT_BF16>
__global__ __launch_bounds__(256) void gemm_bt(const u16* __restrict__ A,
                                               const u16* __restrict__ Bm,
                                               void* __restrict__ C, int N, int K) {
  __shared__ __align__(16) u16 As[2][128 * 64];
  __shared__ __align__(16) u16 Bs[2][128 * 64];
  const int tid = threadIdx.x;
  const int lane = tid & 63, wave = tid >> 6;
  const int quad = lane >> 4, l15 = lane & 15;
  const int wm = (wave >> 1) << 6, wn = (wave & 1) << 6;
  const int m0 = blockIdx.y << 7, n0 = blockIdx.x << 7;

  f32x4 acc[4][4];
#pragma unroll
  for (int i = 0; i < 4; ++i)
#pragma unroll
    for (int j = 0; j < 4; ++j) acc[i][j] = {0.f, 0.f, 0.f, 0.f};

  const int sr = lane >> 3;            // row within 8-row DMA chunk (0..7)
  const int sg = (lane & 7) ^ sr;      // pre-swizzled source granule (16 B)

  // per-lane global source base (row m0/n0 + chunk*8 + sr, col granule sg)
  const u16* asrc = A + (size_t)(m0 + sr) * K + sg * 8;
  const u16* bsrc = Bm + (size_t)(n0 + sr) * K + sg * 8;

  // prologue: stage K-tile 0 into buf 0
#pragma unroll
  for (int it = 0; it < 4; ++it) {
    const int chunk = wave + it * 4;              // 0..15 (8 rows each)
    gload_lds16(asrc + (size_t)(chunk * 8) * K, As[0] + chunk * 512);
    gload_lds16(bsrc + (size_t)(chunk * 8) * K, Bs[0] + chunk * 512);
  }
  __syncthreads();                    // drain prologue DMA

  int cur = 0;
  for (int k0 = 0; k0 < K; k0 += 64, cur ^= 1) {
    // issue next tile's DMA into the idle buffer (its last readers finished
    // at the previous iteration's end barrier)
    if (k0 + 64 < K) {
#pragma unroll
      for (int it = 0; it < 4; ++it) {
        const int chunk = wave + it * 4;
        gload_lds16(asrc + (size_t)(chunk * 8) * K + k0 + 64,
                    As[cur ^ 1] + chunk * 512);
        gload_lds16(bsrc + (size_t)(chunk * 8) * K + k0 + 64,
                    Bs[cur ^ 1] + chunk * 512);
      }
    }
    const u16* as = As[cur];
    const u16* bs = Bs[cur];
#pragma unroll
    for (int ks = 0; ks < 2; ++ks) {
      bf16x8 af[4], bfr[4];
#pragma unroll
      for (int i = 0; i < 4; ++i)
        af[i] = *(const bf16x8*)(as + (wm + i * 16 + l15) * 64 +
                                 (((ks * 4 + quad) ^ (l15 & 7)) * 8));
#pragma unroll
      for (int j = 0; j < 4; ++j)
        bfr[j] = *(const bf16x8*)(bs + (wn + j * 16 + l15) * 64 +
                                  (((ks * 4 + quad) ^ (l15 & 7)) * 8));
#pragma unroll
      for (int i = 0; i < 4; ++i)
#pragma unroll
        for (int j = 0; j < 4; ++j)
          acc[i][j] = __builtin_amdgcn_mfma_f32_16x16x32_bf16(af[i], bfr[j],
                                                              acc[i][j],
                                                              0, 0, 0);
    }
    __syncthreads();   // buf[cur] readers done; buf[cur^1] DMA complete
  }
#pragma unroll
  for (int i = 0; i < 4; ++i) {
    int row = m0 + wm + i * 16 + quad * 4;
#pragma unroll
    for (int j = 0; j < 4; ++j) {
      int col = n0 + wn + j * 16 + l15;
#pragma unroll
      for (int r = 0; r < 4; ++r) {
        if (OUT_BF16)
          ((u16*)C)[(size_t)(row + r) * N + col] = f2bf(acc[i][j][r]);
        else
          ((float*)C)[(size_t)(row + r) * N + col] = acc[i][j][r];
      }
    }
  }
}

// ---------------------------------------------------------------- prep: K-rope + V-transpose
// bid < 4096: K-rope, two (b,l) rows per block (128 threads each: 8 d-chunks
// x 16 heads), 16B/thread, in place. bid >= 4096: V transpose tile (r15
// pack-2 LDS form), q = bid-4096 -> bh = q>>5, lbase = (q&31)<<6.
__global__ __launch_bounds__(256) void prep(u16* __restrict__ qkvb,
                                            u16* __restrict__ Vt) {
  __shared__ uint32_t tile[64 * 36];               // used by transpose blocks
  const int bid = blockIdx.x;
  const int tid = threadIdx.x;
  if (bid < 4096) {                                // ---- K-rope
    const int bl = bid * 2 + (tid >> 7);           // b*L + l
    const int l = bl & (L_ - 1);
    const int t7 = tid & 127;
    const int c = t7 & 7, h = t7 >> 3;
    u16* p = qkvb + (size_t)bl * E3_ + D_ + h * DH_ + c * 8;
    uint4 v = *(const uint4*)p;
    unsigned* w = (unsigned*)&v;
#pragma unroll
    for (int j = 0; j < 4; ++j) {
      const int d2 = c * 4 + j;
      float inv = exp2f((float)d2 * -0.5190512648261504f);
      float ang = (float)l * inv;
      float sn = __sinf(ang), cs = __cosf(ang);
      float x1 = bf2f((u16)(w[j] & 0xffffu)), x2 = bf2f((u16)(w[j] >> 16));
      w[j] = (unsigned)f2bf(x1 * cs - x2 * sn) |
             ((unsigned)f2bf(x2 * cs + x1 * sn) << 16);
    }
    *(uint4*)p = v;
  } else {                                         // ---- V transpose
    const int q = bid - 4096;
    const int bh = q >> 5, b = bh >> 4, h = bh & 15;
    const int lbase = (q & 31) << 6;
    {  // write phase: 256 units = 32 row-pairs x 8 d-chunks
      const int ur = tid >> 3, c = tid & 7;        // l-pair, d-chunk
      const u16* src = qkvb + (size_t)(b * L_ + lbase + 2 * ur) * E3_ +
                       2 * D_ + h * DH_ + c * 8;
      uint4 va = *(const uint4*)src;               // row l = 2*ur
      uint4 vb = *(const uint4*)(src + E3_);       // row l = 2*ur+1
      const unsigned* pa = (const unsigned*)&va;
      const unsigned* pb = (const unsigned*)&vb;
      const int us = ur ^ (c << 2);                // swizzled u32 slot
#pragma unroll
      for (int qq = 0; qq < 4; ++qq) {
        const int d0 = c * 8 + 2 * qq;
        tile[d0 * 36 + us] = (pa[qq] & 0xffffu) | (pb[qq] << 16);
        tile[(d0 + 1) * 36 + us] = (pa[qq] >> 16) | (pb[qq] & 0xffff0000u);
      }
    }
    __syncthreads();
    const uint4* t4 = (const uint4*)tile;
#pragma unroll
    for (int it = 0; it < 2; ++it) {               // 512 units = 64 d x 8 lc
      const int u = it * 256 + tid;
      const int d = u >> 3, lc = u & 7;
      uint4 v = t4[d * 9 + (lc ^ (d >> 3))];
      *(uint4*)(Vt + (size_t)(bh * DH_ + d) * L_ + lbase + lc * 8) = v;
    }
  }
}

// ---------------------------------------------------------------- flash attention (causal)
// grid (8 pairs, B*H), 8 waves x 512 threads; block (p,bh) runs 128-row
// q-tile 15-p then p (uniform 34 k-iters). Wave owns 16 q-rows (1 m-tile).
// Transposed MFMA dataflow: S^T=mfma(kf,qf), O^T=mfma(vf,pf), l=mfma(ones,pf).
// Q-rope applied IN-REGISTER at Q load (fragment = 8 consecutive d = 4 pairs;
// Q scale 1/sqrt(DH)*log2e folded in). K pre-roped by prep.
// K/V: unpadded [64][64] dbuf LDS via global_load_lds + XOR granule swizzle.
__global__ __launch_bounds__(512) void attn(const u16* __restrict__ qkvb,
                                            const u16* __restrict__ Vt,
                                            u16* __restrict__ Ob) {
  __shared__ __align__(16) u16 Ks[2][64 * 64];     // [dbuf][key][d], XOR-swz
  __shared__ __align__(16) u16 Vs[2][64 * 64];     // [dbuf][d][key], XOR-swz
  __shared__ __align__(16) u16 Ps[8][16 * 72];     // per-wave P / O tile [q][.]
  const int bh = blockIdx.y, b = bh >> 4, h = bh & 15;
  const int pair = blockIdx.x;                     // 0..7
  const int tid = threadIdx.x;
  const int lane = tid & 63, wave = tid >> 6, quad = lane >> 4, l15 = lane & 15;
  u16* pw = Ps[wave];

  // DMA staging: wave w covers rows w*8..w*8+7 of the 64-row tile.
  const int srow = wave * 8 + (lane >> 3);          // row this lane sources
  const int sgran = (lane & 7) ^ (lane >> 3);       // pre-swizzled 16B granule
  const u16* ksrc0 =
      qkvb + (size_t)(b * L_ + srow) * E3_ + D_ + h * DH_ + sgran * 8;
  const u16* vsrc0 = Vt + (size_t)(bh * DH_ + srow) * L_ + sgran * 8;
  const int ldst = wave * 512;                      // per-wave uniform LDS dest

  bf16x8 ones;
#pragma unroll
  for (int i = 0; i < 8; ++i) ones[i] = (short)0x3F80;   // bf16 1.0

  for (int a = 0; a < 2; ++a) {
    const int qbase = (a ? pair : (15 - pair)) << 7;   // long tile first
    const int rb = qbase + wave * 16;                  // wave's q-row base
    const int qg = rb + l15;                           // this lane's q row

    // Q fragments (layout [q=l15][k=quad*8+j]) with in-register RoPE:
    // frag f covers d = f*32 + quad*8 + (0..7) -> pairs (2j,2j+1),
    // d2 = f*16 + quad*4 + j, ang = qg * theta^(-d2/32).
    bf16x8 qf[2];
    {
      const u16* qp = qkvb + (size_t)(b * L_ + qg) * E3_ + h * DH_;
      bf16x8 raw0 = *(const bf16x8*)(qp + quad * 8);
      bf16x8 raw1 = *(const bf16x8*)(qp + 32 + quad * 8);
      const float qsc = 0.18033688011112042f;       // 1/sqrt(64)*log2(e)
#pragma unroll
      for (int f = 0; f < 2; ++f) {
        bf16x8 raw = f ? raw1 : raw0;
        bf16x8 o;
#pragma unroll
        for (int j = 0; j < 4; ++j) {
          const int d2 = f * 16 + quad * 4 + j;
          float inv = exp2f((float)d2 * -0.5190512648261504f);
          float ang = (float)qg * inv;
          float sn = __sinf(ang), cs = __cosf(ang);
          float x1 = bf2f((u16)raw[2 * j]), x2 = bf2f((u16)raw[2 * j + 1]);
          o[2 * j] = (short)f2bf((x1 * cs - x2 * sn) * qsc);
          o[2 * j + 1] = (short)f2bf((x2 * cs + x1 * sn) * qsc);
        }
        qf[f] = o;
      }
    }

    f32x4 acc[4], lacc;                // O^T tile + l (col q=l15)
    lacc = {0.f, 0.f, 0.f, 0.f};
#pragma unroll
    for (int j = 0; j < 4; ++j) acc[j] = {0.f, 0.f, 0.f, 0.f};

    // prologue: DMA k-tile 0 into buf 0
    gload_lds16(ksrc0, Ks[0] + ldst);
    gload_lds16(vsrc0, Vs[0] + ldst);
    __syncthreads();                   // drain DMA (vmcnt 0) + rendezvous

    const int kend = qbase + 128;
    int cur = 0;
    for (int kb = 0; kb < kend; kb += 64, cur ^= 1) {
      // issue DMA for next tile into the idle buffer (free since the barrier
      // at the end of iter kb-64 separated its last readers)
      if (kb + 64 < kend) {
        gload_lds16(ksrc0 + (size_t)(kb + 64) * E3_, Ks[cur ^ 1] + ldst);
        gload_lds16(vsrc0 + (kb + 64), Vs[cur ^ 1] + ldst);
      }
      const u16* kcur = Ks[cur];
      const u16* vcur = Vs[cur];

      // S^T = mfma(kf, qf): lane holds col q=l15, rows key=t*16+quad*4+r
      f32x4 st[4];
#pragma unroll
      for (int t = 0; t < 4; ++t) st[t] = {0.f, 0.f, 0.f, 0.f};
      __builtin_amdgcn_s_setprio(1);
#pragma unroll
      for (int ks = 0; ks < 2; ++ks) {
        bf16x8 kf[4];
#pragma unroll
        for (int t = 0; t < 4; ++t)
          kf[t] = *(const bf16x8*)(kcur + (t * 16 + l15) * 64 +
                                   (((ks * 4 + quad) ^ (l15 & 7)) * 8));
#pragma unroll
        for (int t = 0; t < 4; ++t)
          st[t] = __builtin_amdgcn_mfma_f32_16x16x32_bf16(kf[t], qf[ks],
                                                          st[t], 0, 0, 0);
      }
      __builtin_amdgcn_s_setprio(0);

      // p = exp2(s) (masked -> 0), packed b64 store to P[q][key]
      {
        const bool dg = (kb + 63 > rb);          // diagonal overlap
#pragma unroll
        for (int t = 0; t < 4; ++t) {
          const int kg0 = kb + t * 16 + quad * 4;
          float p0, p1, p2, p3;
          if (dg) {
            p0 = (kg0 + 0 > qg) ? 0.f : fexp2(st[t][0]);
            p1 = (kg0 + 1 > qg) ? 0.f : fexp2(st[t][1]);
            p2 = (kg0 + 2 > qg) ? 0.f : fexp2(st[t][2]);
            p3 = (kg0 + 3 > qg) ? 0.f : fexp2(st[t][3]);
          } else {
            p0 = fexp2(st[t][0]);
            p1 = fexp2(st[t][1]);
            p2 = fexp2(st[t][2]);
            p3 = fexp2(st[t][3]);
          }
          uint2 pkd = {pk2(p0, p1), pk2(p2, p3)};
          *(uint2*)(pw + l15 * 72 + t * 16 + quad * 4) = pkd;
        }
      }
      // same-wave LDS write -> read ordering without draining the DMA (vmcnt)
      asm volatile("s_waitcnt lgkmcnt(0)" ::: "memory");
      __builtin_amdgcn_sched_barrier(0);

      // O^T += mfma(vf, pf) ; l += mfma(ones, pf)
      __builtin_amdgcn_s_setprio(1);
#pragma unroll
      for (int ks = 0; ks < 2; ++ks) {
        bf16x8 vf[4];
#pragma unroll
        for (int j = 0; j < 4; ++j)
          vf[j] = *(const bf16x8*)(vcur + (j * 16 + l15) * 64 +
                                   (((ks * 4 + quad) ^ (l15 & 7)) * 8));
        bf16x8 pf = *(const bf16x8*)(pw + l15 * 72 + ks * 32 + quad * 8);
        lacc = __builtin_amdgcn_mfma_f32_16x16x32_bf16(ones, pf, lacc,
                                                       0, 0, 0);
#pragma unroll
        for (int j = 0; j < 4; ++j)
          acc[j] = __builtin_amdgcn_mfma_f32_16x16x32_bf16(vf[j], pf,
                                                           acc[j], 0, 0, 0);
      }
      __builtin_amdgcn_s_setprio(0);

      __syncthreads();   // buf[cur] readers done; buf[cur^1] DMA complete
    }

    // epilogue: O^T lane holds col q=l15, rows d=j*16+quad*4+r; lacc uniform
    // across regs -> one reciprocal per wave; packed b64 stores to [q][d].
    {
      const float rl = 1.0f / lacc[0];
#pragma unroll
      for (int j = 0; j < 4; ++j) {
        uint2 od = {pk2(acc[j][0] * rl, acc[j][1] * rl),
                    pk2(acc[j][2] * rl, acc[j][3] * rl)};
        *(uint2*)(pw + l15 * 72 + j * 16 + quad * 4) = od;
      }
    }
    __syncthreads();   // all waves' O tiles staged
#pragma unroll
    for (int it = 0; it < 2; ++it) {
      int unit = it * 512 + tid;                 // 1024 units = 128 rows x 8
      int row = unit >> 3, ch = (unit & 7) * 8;
      *(uint4*)(Ob + (size_t)(b * L_ + qbase + row) * D_ + h * DH_ + ch) =
          *(const uint4*)(Ps[row >> 4] + (row & 15) * 72 + ch);
    }
    __syncthreads();   // store reads done before next tile overwrites Ps
  }
}

// ---------------------------------------------------------------- launch
extern "C" void kernel_launch(void* const* d_in, const int* in_sizes, int n_in,
                              void* d_out, int out_size, void* d_ws, size_t ws_size,
                              hipStream_t stream) {
  const float* x  = (const float*)d_in[0];
  const float* W  = (const float*)d_in[1];
  const float* Wo = (const float*)d_in[2];
  float* out = (float*)d_out;

  char* ws = (char*)d_ws;
  u16* xb   = (u16*)(ws);                    // 16,777,216
  u16* Wb   = (u16*)(ws + 16777216);         //  6,291,456
  u16* Wob  = (u16*)(ws + 23068672);         //  2,097,152
  u16* qkvb = (u16*)(ws + 25165824);         // 50,331,648  (B,L,3,H,DH) bf16
  u16* Vt   = (u16*)(ws + 75497472);         // 16,777,216  (B,H,DH,L) bf16
  u16* Ob   = (u16*)(ws + 92274688);         // 16,777,216  (B,L,D) bf16

  cvt_all<<<6144, 256, 0, stream>>>(x, W, Wo, xb, Wb, Wob);

  gemm_bt<true><<<dim3(E3_ / 128, (B_ * L_) / 128), 256, 0, stream>>>(
      xb, Wb, qkvb, E3_, D_);

  prep<<<4096 + 2048, 256, 0, stream>>>(qkvb, Vt);

  attn<<<dim3(8, B_ * H_), 512, 0, stream>>>(qkvb, Vt, Ob);

  gemm_bt<false><<<dim3(D_ / 128, (B_ * L_) / 128), 256, 0, stream>>>(
      Ob, Wob, out, D_, D_);
}

// Round 13
// 234.991 us; speedup vs baseline: 1.0280x; 1.0280x over previous
//
#include <hip/hip_runtime.h>
#include <cstddef>
#include <cstdint>

// ---------------------------------------------------------------------------
// MultiHeadSelfAttention: x(4,2048,1024) fp32, W(3072,1024) fp32, Wo(1024,1024)
// Pipeline (5 launches): cvt_all | GEMM1 qkv | prep (K-rope + V-transpose) |
// flash attn (Q-rope in-register) | GEMM2
// r23: attn XCD-aware block remap (T1). The 8 pair-blocks of one bh read
// identical K/V but linear dispatch round-robins them across the 8 XCD L2s
// -> measured 147.5 MB FETCH vs ~50 MB unique (3x over-fetch). Remap
// lin = by*8+bx: xcd=lin&7, bh=(lin&7)*8+((lin>>3)&7), pair=lin>>6 ->
// all 8 pairs of a bh on ONE XCD (lin = c+8d+64p ≡ c mod 8). Bijective,
// uniform load preserved. GEMM dbuf (r22, neutral-kept), cvt/prep unchanged.
// ---------------------------------------------------------------------------

typedef unsigned short u16;
typedef short bf16x8 __attribute__((ext_vector_type(8)));   // 8 bf16 = 4 VGPRs
typedef float f32x4 __attribute__((ext_vector_type(4)));

#define B_   4
#define L_   2048
#define H_   16
#define DH_  64
#define D_   1024
#define E3_  3072

__device__ __forceinline__ u16 f2bf(float f) {            // RNE f32 -> bf16
  unsigned int u = __float_as_uint(f);
  u += 0x7fffu + ((u >> 16) & 1u);
  return (u16)(u >> 16);
}
__device__ __forceinline__ float bf2f(u16 h) {
  return __uint_as_float(((unsigned int)h) << 16);
}
// round-half-up pack of two f32 -> bf16x2 (5 VALU ops)
__device__ __forceinline__ unsigned pk2(float a, float b) {
  return ((__float_as_uint(a) + 0x8000u) >> 16) |
         ((__float_as_uint(b) + 0x8000u) & 0xffff0000u);
}
__device__ __forceinline__ float fexp2(float x) {
#if __has_builtin(__builtin_amdgcn_exp2f)
  return __builtin_amdgcn_exp2f(x);
#else
  return exp2f(x);
#endif
}

// async global->LDS DMA, 16 bytes/lane. LDS dest = wave-uniform base + lane*16
__device__ __forceinline__ void gload_lds16(const void* g, void* l) {
  auto gp = reinterpret_cast<const uint32_t __attribute__((address_space(1)))*>(
      reinterpret_cast<uintptr_t>(g));
  auto lp = reinterpret_cast<uint32_t __attribute__((address_space(3)))*>(
      reinterpret_cast<uintptr_t>(l));
  __builtin_amdgcn_global_load_lds(gp, lp, 16, 0, 0);
}

// ---------------------------------------------------------------- cvt fp32->bf16 (x | W | Wo)
// flat 16B-unit index over all three buffers: 1048576 + 393216 + 131072 =
// 1572864 = 6144 blocks x 256 (exact, no bounds check).
__global__ __launch_bounds__(256) void cvt_all(const float* __restrict__ x,
                                               const float* __restrict__ W,
                                               const float* __restrict__ Wo,
                                               u16* __restrict__ xb,
                                               u16* __restrict__ Wb,
                                               u16* __restrict__ Wob) {
  int i = blockIdx.x * 256 + threadIdx.x;
  const float* in;
  u16* out;
  int off;
  if (i < 1048576) {
    in = x; out = xb; off = i;
  } else if (i < 1441792) {
    in = W; out = Wb; off = i - 1048576;
  } else {
    in = Wo; out = Wob; off = i - 1441792;
  }
  const float4* p = (const float4*)in;
  float4 a = p[2 * off], b = p[2 * off + 1];
  uint4 o;
  o.x = (unsigned)f2bf(a.x) | ((unsigned)f2bf(a.y) << 16);
  o.y = (unsigned)f2bf(a.z) | ((unsigned)f2bf(a.w) << 16);
  o.z = (unsigned)f2bf(b.x) | ((unsigned)f2bf(b.y) << 16);
  o.w = (unsigned)f2bf(b.z) | ((unsigned)f2bf(b.w) << 16);
  ((uint4*)out)[off] = o;
}

// ---------------------------------------------------------------- GEMM C = A * B^T
// 128x128 block tile, 4 waves (2x2 of 64x64), BK=64, double-buffered DMA:
// issue DMA(t+1) -> MFMA tile t -> one barrier. global_load_lds width=16,
// linear dest, XOR granule swizzle (source pre-swizzled (l&7)^(l>>3), read
// granule (ks*4+quad)^(l15&7); conflict-free, measured 0 in r21).
template <bool OUT_BF16>
__global__ __launch_bounds__(256) void gemm_bt(const u16* __restrict__ A,
                                               const u16* __restrict__ Bm,
                                               void* __restrict__ C, int N, int K) {
  __shared__ __align__(16) u16 As[2][128 * 64];
  __shared__ __align__(16) u16 Bs[2][128 * 64];
  const int tid = threadIdx.x;
  const int lane = tid & 63, wave = tid >> 6;
  const int quad = lane >> 4, l15 = lane & 15;
  const int wm = (wave >> 1) << 6, wn = (wave & 1) << 6;
  const int m0 = blockIdx.y << 7, n0 = blockIdx.x << 7;

  f32x4 acc[4][4];
#pragma unroll
  for (int i = 0; i < 4; ++i)
#pragma unroll
    for (int j = 0; j < 4; ++j) acc[i][j] = {0.f, 0.f, 0.f, 0.f};

  const int sr = lane >> 3;            // row within 8-row DMA chunk (0..7)
  const int sg = (lane & 7) ^ sr;      // pre-swizzled source granule (16 B)

  // per-lane global source base (row m0/n0 + chunk*8 + sr, col granule sg)
  const u16* asrc = A + (size_t)(m0 + sr) * K + sg * 8;
  const u16* bsrc = Bm + (size_t)(n0 + sr) * K + sg * 8;

  // prologue: stage K-tile 0 into buf 0
#pragma unroll
  for (int it = 0; it < 4; ++it) {
    const int chunk = wave + it * 4;              // 0..15 (8 rows each)
    gload_lds16(asrc + (size_t)(chunk * 8) * K, As[0] + chunk * 512);
    gload_lds16(bsrc + (size_t)(chunk * 8) * K, Bs[0] + chunk * 512);
  }
  __syncthreads();                    // drain prologue DMA

  int cur = 0;
  for (int k0 = 0; k0 < K; k0 += 64, cur ^= 1) {
    // issue next tile's DMA into the idle buffer (its last readers finished
    // at the previous iteration's end barrier)
    if (k0 + 64 < K) {
#pragma unroll
      for (int it = 0; it < 4; ++it) {
        const int chunk = wave + it * 4;
        gload_lds16(asrc + (size_t)(chunk * 8) * K + k0 + 64,
                    As[cur ^ 1] + chunk * 512);
        gload_lds16(bsrc + (size_t)(chunk * 8) * K + k0 + 64,
                    Bs[cur ^ 1] + chunk * 512);
      }
    }
    const u16* as = As[cur];
    const u16* bs = Bs[cur];
#pragma unroll
    for (int ks = 0; ks < 2; ++ks) {
      bf16x8 af[4], bfr[4];
#pragma unroll
      for (int i = 0; i < 4; ++i)
        af[i] = *(const bf16x8*)(as + (wm + i * 16 + l15) * 64 +
                                 (((ks * 4 + quad) ^ (l15 & 7)) * 8));
#pragma unroll
      for (int j = 0; j < 4; ++j)
        bfr[j] = *(const bf16x8*)(bs + (wn + j * 16 + l15) * 64 +
                                  (((ks * 4 + quad) ^ (l15 & 7)) * 8));
#pragma unroll
      for (int i = 0; i < 4; ++i)
#pragma unroll
        for (int j = 0; j < 4; ++j)
          acc[i][j] = __builtin_amdgcn_mfma_f32_16x16x32_bf16(af[i], bfr[j],
                                                              acc[i][j],
                                                              0, 0, 0);
    }
    __syncthreads();   // buf[cur] readers done; buf[cur^1] DMA complete
  }
#pragma unroll
  for (int i = 0; i < 4; ++i) {
    int row = m0 + wm + i * 16 + quad * 4;
#pragma unroll
    for (int j = 0; j < 4; ++j) {
      int col = n0 + wn + j * 16 + l15;
#pragma unroll
      for (int r = 0; r < 4; ++r) {
        if (OUT_BF16)
          ((u16*)C)[(size_t)(row + r) * N + col] = f2bf(acc[i][j][r]);
        else
          ((float*)C)[(size_t)(row + r) * N + col] = acc[i][j][r];
      }
    }
  }
}

// ---------------------------------------------------------------- prep: K-rope + V-transpose
// bid < 4096: K-rope, two (b,l) rows per block (128 threads each: 8 d-chunks
// x 16 heads), 16B/thread, in place. bid >= 4096: V transpose tile (r15
// pack-2 LDS form), q = bid-4096 -> bh = q>>5, lbase = (q&31)<<6.
__global__ __launch_bounds__(256) void prep(u16* __restrict__ qkvb,
                                            u16* __restrict__ Vt) {
  __shared__ uint32_t tile[64 * 36];               // used by transpose blocks
  const int bid = blockIdx.x;
  const int tid = threadIdx.x;
  if (bid < 4096) {                                // ---- K-rope
    const int bl = bid * 2 + (tid >> 7);           // b*L + l
    const int l = bl & (L_ - 1);
    const int t7 = tid & 127;
    const int c = t7 & 7, h = t7 >> 3;
    u16* p = qkvb + (size_t)bl * E3_ + D_ + h * DH_ + c * 8;
    uint4 v = *(const uint4*)p;
    unsigned* w = (unsigned*)&v;
#pragma unroll
    for (int j = 0; j < 4; ++j) {
      const int d2 = c * 4 + j;
      float inv = exp2f((float)d2 * -0.5190512648261504f);
      float ang = (float)l * inv;
      float sn = __sinf(ang), cs = __cosf(ang);
      float x1 = bf2f((u16)(w[j] & 0xffffu)), x2 = bf2f((u16)(w[j] >> 16));
      w[j] = (unsigned)f2bf(x1 * cs - x2 * sn) |
             ((unsigned)f2bf(x2 * cs + x1 * sn) << 16);
    }
    *(uint4*)p = v;
  } else {                                         // ---- V transpose
    const int q = bid - 4096;
    const int bh = q >> 5, b = bh >> 4, h = bh & 15;
    const int lbase = (q & 31) << 6;
    {  // write phase: 256 units = 32 row-pairs x 8 d-chunks
      const int ur = tid >> 3, c = tid & 7;        // l-pair, d-chunk
      const u16* src = qkvb + (size_t)(b * L_ + lbase + 2 * ur) * E3_ +
                       2 * D_ + h * DH_ + c * 8;
      uint4 va = *(const uint4*)src;               // row l = 2*ur
      uint4 vb = *(const uint4*)(src + E3_);       // row l = 2*ur+1
      const unsigned* pa = (const unsigned*)&va;
      const unsigned* pb = (const unsigned*)&vb;
      const int us = ur ^ (c << 2);                // swizzled u32 slot
#pragma unroll
      for (int qq = 0; qq < 4; ++qq) {
        const int d0 = c * 8 + 2 * qq;
        tile[d0 * 36 + us] = (pa[qq] & 0xffffu) | (pb[qq] << 16);
        tile[(d0 + 1) * 36 + us] = (pa[qq] >> 16) | (pb[qq] & 0xffff0000u);
      }
    }
    __syncthreads();
    const uint4* t4 = (const uint4*)tile;
#pragma unroll
    for (int it = 0; it < 2; ++it) {               // 512 units = 64 d x 8 lc
      const int u = it * 256 + tid;
      const int d = u >> 3, lc = u & 7;
      uint4 v = t4[d * 9 + (lc ^ (d >> 3))];
      *(uint4*)(Vt + (size_t)(bh * DH_ + d) * L_ + lbase + lc * 8) = v;
    }
  }
}

// ---------------------------------------------------------------- flash attention (causal)
// 512 blocks x 512 threads (8 waves). XCD-aware remap (r23): lin = by*8+bx;
// pair = lin>>6, bh = (lin&7)*8 + ((lin>>3)&7) -> the 8 pair-blocks of each
// bh satisfy lin ≡ const (mod 8) => same XCD L2; K/V fetched once per XCD.
// Block runs 128-row q-tile (15-pair) then pair (uniform 34 k-iters); wave
// owns 16 q-rows. Transposed MFMA dataflow; Q-rope in-register at Q load;
// K pre-roped. K/V: unpadded [64][64] dbuf LDS via global_load_lds + XOR
// granule swizzle. One barrier per k-iter.
__global__ __launch_bounds__(512) void attn(const u16* __restrict__ qkvb,
                                            const u16* __restrict__ Vt,
                                            u16* __restrict__ Ob) {
  __shared__ __align__(16) u16 Ks[2][64 * 64];     // [dbuf][key][d], XOR-swz
  __shared__ __align__(16) u16 Vs[2][64 * 64];     // [dbuf][d][key], XOR-swz
  __shared__ __align__(16) u16 Ps[8][16 * 72];     // per-wave P / O tile [q][.]
  const int lin = blockIdx.y * 8 + blockIdx.x;     // 0..511
  const int pair = lin >> 6;                       // 0..7
  const int bh = (lin & 7) * 8 + ((lin >> 3) & 7); // same-XCD bh grouping
  const int b = bh >> 4, h = bh & 15;
  const int tid = threadIdx.x;
  const int lane = tid & 63, wave = tid >> 6, quad = lane >> 4, l15 = lane & 15;
  u16* pw = Ps[wave];

  // DMA staging: wave w covers rows w*8..w*8+7 of the 64-row tile.
  const int srow = wave * 8 + (lane >> 3);          // row this lane sources
  const int sgran = (lane & 7) ^ (lane >> 3);       // pre-swizzled 16B granule
  const u16* ksrc0 =
      qkvb + (size_t)(b * L_ + srow) * E3_ + D_ + h * DH_ + sgran * 8;
  const u16* vsrc0 = Vt + (size_t)(bh * DH_ + srow) * L_ + sgran * 8;
  const int ldst = wave * 512;                      // per-wave uniform LDS dest

  bf16x8 ones;
#pragma unroll
  for (int i = 0; i < 8; ++i) ones[i] = (short)0x3F80;   // bf16 1.0

  for (int a = 0; a < 2; ++a) {
    const int qbase = (a ? pair : (15 - pair)) << 7;   // long tile first
    const int rb = qbase + wave * 16;                  // wave's q-row base
    const int qg = rb + l15;                           // this lane's q row

    // Q fragments (layout [q=l15][k=quad*8+j]) with in-register RoPE:
    // frag f covers d = f*32 + quad*8 + (0..7) -> pairs (2j,2j+1),
    // d2 = f*16 + quad*4 + j, ang = qg * theta^(-d2/32).
    bf16x8 qf[2];
    {
      const u16* qp = qkvb + (size_t)(b * L_ + qg) * E3_ + h * DH_;
      bf16x8 raw0 = *(const bf16x8*)(qp + quad * 8);
      bf16x8 raw1 = *(const bf16x8*)(qp + 32 + quad * 8);
      const float qsc = 0.18033688011112042f;       // 1/sqrt(64)*log2(e)
#pragma unroll
      for (int f = 0; f < 2; ++f) {
        bf16x8 raw = f ? raw1 : raw0;
        bf16x8 o;
#pragma unroll
        for (int j = 0; j < 4; ++j) {
          const int d2 = f * 16 + quad * 4 + j;
          float inv = exp2f((float)d2 * -0.5190512648261504f);
          float ang = (float)qg * inv;
          float sn = __sinf(ang), cs = __cosf(ang);
          float x1 = bf2f((u16)raw[2 * j]), x2 = bf2f((u16)raw[2 * j + 1]);
          o[2 * j] = (short)f2bf((x1 * cs - x2 * sn) * qsc);
          o[2 * j + 1] = (short)f2bf((x2 * cs + x1 * sn) * qsc);
        }
        qf[f] = o;
      }
    }

    f32x4 acc[4], lacc;                // O^T tile + l (col q=l15)
    lacc = {0.f, 0.f, 0.f, 0.f};
#pragma unroll
    for (int j = 0; j < 4; ++j) acc[j] = {0.f, 0.f, 0.f, 0.f};

    // prologue: DMA k-tile 0 into buf 0
    gload_lds16(ksrc0, Ks[0] + ldst);
    gload_lds16(vsrc0, Vs[0] + ldst);
    __syncthreads();                   // drain DMA (vmcnt 0) + rendezvous

    const int kend = qbase + 128;
    int cur = 0;
    for (int kb = 0; kb < kend; kb += 64, cur ^= 1) {
      // issue DMA for next tile into the idle buffer (free since the barrier
      // at the end of iter kb-64 separated its last readers)
      if (kb + 64 < kend) {
        gload_lds16(ksrc0 + (size_t)(kb + 64) * E3_, Ks[cur ^ 1] + ldst);
        gload_lds16(vsrc0 + (kb + 64), Vs[cur ^ 1] + ldst);
      }
      const u16* kcur = Ks[cur];
      const u16* vcur = Vs[cur];

      // S^T = mfma(kf, qf): lane holds col q=l15, rows key=t*16+quad*4+r
      f32x4 st[4];
#pragma unroll
      for (int t = 0; t < 4; ++t) st[t] = {0.f, 0.f, 0.f, 0.f};
      __builtin_amdgcn_s_setprio(1);
#pragma unroll
      for (int ks = 0; ks < 2; ++ks) {
        bf16x8 kf[4];
#pragma unroll
        for (int t = 0; t < 4; ++t)
          kf[t] = *(const bf16x8*)(kcur + (t * 16 + l15) * 64 +
                                   (((ks * 4 + quad) ^ (l15 & 7)) * 8));
#pragma unroll
        for (int t = 0; t < 4; ++t)
          st[t] = __builtin_amdgcn_mfma_f32_16x16x32_bf16(kf[t], qf[ks],
                                                          st[t], 0, 0, 0);
      }
      __builtin_amdgcn_s_setprio(0);

      // p = exp2(s) (masked -> 0), packed b64 store to P[q][key]
      {
        const bool dg = (kb + 63 > rb);          // diagonal overlap
#pragma unroll
        for (int t = 0; t < 4; ++t) {
          const int kg0 = kb + t * 16 + quad * 4;
          float p0, p1, p2, p3;
          if (dg) {
            p0 = (kg0 + 0 > qg) ? 0.f : fexp2(st[t][0]);
            p1 = (kg0 + 1 > qg) ? 0.f : fexp2(st[t][1]);
            p2 = (kg0 + 2 > qg) ? 0.f : fexp2(st[t][2]);
            p3 = (kg0 + 3 > qg) ? 0.f : fexp2(st[t][3]);
          } else {
            p0 = fexp2(st[t][0]);
            p1 = fexp2(st[t][1]);
            p2 = fexp2(st[t][2]);
            p3 = fexp2(st[t][3]);
          }
          uint2 pkd = {pk2(p0, p1), pk2(p2, p3)};
          *(uint2*)(pw + l15 * 72 + t * 16 + quad * 4) = pkd;
        }
      }
      // same-wave LDS write -> read ordering without draining the DMA (vmcnt)
      asm volatile("s_waitcnt lgkmcnt(0)" ::: "memory");
      __builtin_amdgcn_sched_barrier(0);

      // O^T += mfma(vf, pf) ; l += mfma(ones, pf)
      __builtin_amdgcn_s_setprio(1);
#pragma unroll
      for (int ks = 0; ks < 2; ++ks) {
        bf16x8 vf[4];
#pragma unroll
        for (int j = 0; j < 4; ++j)
          vf[j] = *(const bf16x8*)(vcur + (j * 16 + l15) * 64 +
                                   (((ks * 4 + quad) ^ (l15 & 7)) * 8));
        bf16x8 pf = *(const bf16x8*)(pw + l15 * 72 + ks * 32 + quad * 8);
        lacc = __builtin_amdgcn_mfma_f32_16x16x32_bf16(ones, pf, lacc,
                                                       0, 0, 0);
#pragma unroll
        for (int j = 0; j < 4; ++j)
          acc[j] = __builtin_amdgcn_mfma_f32_16x16x32_bf16(vf[j], pf,
                                                           acc[j], 0, 0, 0);
      }
      __builtin_amdgcn_s_setprio(0);

      __syncthreads();   // buf[cur] readers done; buf[cur^1] DMA complete
    }

    // epilogue: O^T lane holds col q=l15, rows d=j*16+quad*4+r; lacc uniform
    // across regs -> one reciprocal per wave; packed b64 stores to [q][d].
    {
      const float rl = 1.0f / lacc[0];
#pragma unroll
      for (int j = 0; j < 4; ++j) {
        uint2 od = {pk2(acc[j][0] * rl, acc[j][1] * rl),
                    pk2(acc[j][2] * rl, acc[j][3] * rl)};
        *(uint2*)(pw + l15 * 72 + j * 16 + quad * 4) = od;
      }
    }
    __syncthreads();   // all waves' O tiles staged
#pragma unroll
    for (int it = 0; it < 2; ++it) {
      int unit = it * 512 + tid;                 // 1024 units = 128 rows x 8
      int row = unit >> 3, ch = (unit & 7) * 8;
      *(uint4*)(Ob + (size_t)(b * L_ + qbase + row) * D_ + h * DH_ + ch) =
          *(const uint4*)(Ps[row >> 4] + (row & 15) * 72 + ch);
    }
    __syncthreads();   // store reads done before next tile overwrites Ps
  }
}

// ---------------------------------------------------------------- launch
extern "C" void kernel_launch(void* const* d_in, const int* in_sizes, int n_in,
                              void* d_out, int out_size, void* d_ws, size_t ws_size,
                              hipStream_t stream) {
  const float* x  = (const float*)d_in[0];
  const float* W  = (const float*)d_in[1];
  const float* Wo = (const float*)d_in[2];
  float* out = (float*)d_out;

  char* ws = (char*)d_ws;
  u16* xb   = (u16*)(ws);                    // 16,777,216
  u16* Wb   = (u16*)(ws + 16777216);         //  6,291,456
  u16* Wob  = (u16*)(ws + 23068672);         //  2,097,152
  u16* qkvb = (u16*)(ws + 25165824);         // 50,331,648  (B,L,3,H,DH) bf16
  u16* Vt   = (u16*)(ws + 75497472);         // 16,777,216  (B,H,DH,L) bf16
  u16* Ob   = (u16*)(ws + 92274688);         // 16,777,216  (B,L,D) bf16

  cvt_all<<<6144, 256, 0, stream>>>(x, W, Wo, xb, Wb, Wob);

  gemm_bt<true><<<dim3(E3_ / 128, (B_ * L_) / 128), 256, 0, stream>>>(
      xb, Wb, qkvb, E3_, D_);

  prep<<<4096 + 2048, 256, 0, stream>>>(qkvb, Vt);

  attn<<<dim3(8, B_ * H_), 512, 0, stream>>>(qkvb, Vt, Ob);

  gemm_bt<false><<<dim3(D_ / 128, (B_ * L_) / 128), 256, 0, stream>>>(
      Ob, Wob, out, D_, D_);
}